// Round 3
// baseline (392.442 us; speedup 1.0000x reference)
//
#include <hip/hip_runtime.h>
#include <hip/hip_bf16.h>

typedef __bf16 bf16x8 __attribute__((ext_vector_type(8)));
typedef __bf16 bf16x4 __attribute__((ext_vector_type(4)));
typedef float  f32x4  __attribute__((ext_vector_type(4)));

#define MFMA16(a, b, c) __builtin_amdgcn_mfma_f32_16x16x32_bf16((a), (b), (c), 0, 0, 0)
#define GLD16(g, l)                                                              \
    __builtin_amdgcn_global_load_lds(                                            \
        (const __attribute__((address_space(1))) void*)(g),                      \
        (__attribute__((address_space(3))) void*)(l), 16, 0, 0)

// ---------------- fp32 -> bf16 convert (vectorized, grid-stride) ----------------
__global__ __launch_bounds__(256) void cvt_f32_bf16(const float* __restrict__ in,
                                                    __bf16* __restrict__ out, int n) {
    int stride = gridDim.x * blockDim.x * 4;
    for (int i = (blockIdx.x * blockDim.x + threadIdx.x) * 4; i < n; i += stride) {
        float4 v = *(const float4*)(in + i);
        bf16x4 o;
        o[0] = (__bf16)v.x; o[1] = (__bf16)v.y; o[2] = (__bf16)v.z; o[3] = (__bf16)v.w;
        *(bf16x4*)(out + i) = o;
    }
}

// ---------------- QKV GEMM (m97 structure): [8192,1024] @ [3072,1024]^T + bias ----
__global__ __launch_bounds__(256, 2) void qkv_gemm(const __bf16* __restrict__ X,
                                                   const __bf16* __restrict__ W,
                                                   const float* __restrict__ bias,
                                                   __bf16* __restrict__ Qo,
                                                   __bf16* __restrict__ Ko,
                                                   __bf16* __restrict__ VTo) {
    const int KD = 1024;
    __shared__ __align__(16) __bf16 As[128 * 32];
    __shared__ __align__(16) __bf16 Bs[128 * 32];
    const int tid = threadIdx.x;
    const int lane = tid & 63, w = tid >> 6;
    const int lr = lane & 15, lg = lane >> 4;
    const int row0 = blockIdx.y * 128, col0 = blockIdx.x * 128;
    const int wrow = (w >> 1) * 64, wcol = (w & 1) * 64;
    f32x4 acc[4][4] = {};
    const int c0 = tid, c1 = tid + 256;
    const __bf16* ga0 = X + (size_t)(row0 + (c0 >> 2)) * KD + (c0 & 3) * 8;
    const __bf16* ga1 = X + (size_t)(row0 + (c1 >> 2)) * KD + (c1 & 3) * 8;
    const __bf16* gb0 = W + (size_t)(col0 + (c0 >> 2)) * KD + (c0 & 3) * 8;
    const __bf16* gb1 = W + (size_t)(col0 + (c1 >> 2)) * KD + (c1 & 3) * 8;
    for (int k0 = 0; k0 < KD; k0 += 32) {
        __syncthreads();
        GLD16(ga0 + k0, As + c0 * 8);
        GLD16(ga1 + k0, As + c1 * 8);
        GLD16(gb0 + k0, Bs + c0 * 8);
        GLD16(gb1 + k0, Bs + c1 * 8);
        __syncthreads();
        bf16x8 a[4], b[4];
#pragma unroll
        for (int mi = 0; mi < 4; mi++)
            a[mi] = *(const bf16x8*)&As[(wrow + mi * 16 + lr) * 32 + lg * 8];
#pragma unroll
        for (int ni = 0; ni < 4; ni++)
            b[ni] = *(const bf16x8*)&Bs[(wcol + ni * 16 + lr) * 32 + lg * 8];
#pragma unroll
        for (int mi = 0; mi < 4; mi++)
#pragma unroll
            for (int ni = 0; ni < 4; ni++)
                acc[mi][ni] = MFMA16(a[mi], b[ni], acc[mi][ni]);
    }
#pragma unroll
    for (int mi = 0; mi < 4; mi++)
#pragma unroll
        for (int ni = 0; ni < 4; ni++)
#pragma unroll
            for (int r = 0; r < 4; r++) {
                int m = row0 + wrow + mi * 16 + lg * 4 + r;  // token row
                int n = col0 + wcol + ni * 16 + lr;          // channel (0..3071)
                float v = acc[mi][ni][r] + bias[n];
                int b_ = m >> 11, t = m & 2047;
                int sec = n >> 10, c = n & 1023;
                int h = c >> 6, d = c & 63;
                int bh = b_ * 16 + h;
                __bf16 bv = (__bf16)v;
                if (sec == 0)      Qo[(size_t)(bh * 2048 + t) * 64 + d] = bv;
                else if (sec == 1) Ko[(size_t)(bh * 2048 + t) * 64 + d] = bv;
                else               VTo[(size_t)(bh * 64 + d) * 2048 + t] = bv;
            }
}

// ---------------- causal flash attention (QBLK=16, balanced pair schedule) -------
// 128 q-tiles of 16 rows per bh; wave handles pair {idx, 127-idx} -> 33 +/- 1
// k-blocks of 64 per wave, uniform. 4096 waves total (4 blocks/CU -> 16 waves/CU).
__global__ __launch_bounds__(256) void attn_kernel(const __bf16* __restrict__ Q,
                                                   const __bf16* __restrict__ Km,
                                                   const __bf16* __restrict__ VT,
                                                   __bf16* __restrict__ ATT) {
    const int T = 2048, D = 64;
    __shared__ __align__(16) __bf16 plds[4][16][68];  // padded: conflict-free
    const int lane = threadIdx.x & 63, w = threadIdx.x >> 6;
    const int lr = lane & 15, lg = lane >> 4;
    const int bh = blockIdx.y;
    const int idx = blockIdx.x * 4 + w;  // 0..63
    const int b_ = bh >> 4, h = bh & 15;
    const __bf16* Qp = Q + (size_t)bh * T * D;
    const __bf16* Kp = Km + (size_t)bh * T * D;
    const __bf16* Vp = VT + (size_t)bh * D * T;

    for (int ph = 0; ph < 2; ++ph) {
        const int j = ph ? 127 - idx : idx;
        const int qrow0 = j * 16;
        bf16x8 qa[2];
#pragma unroll
        for (int dk = 0; dk < 2; dk++)
            qa[dk] = *(const bf16x8*)(Qp + (size_t)(qrow0 + lr) * D + dk * 32 + lg * 8);

        float mrow[4], lrow[4];
#pragma unroll
        for (int r = 0; r < 4; r++) { mrow[r] = -1e30f; lrow[r] = 0.f; }
        f32x4 o[4] = {};

        const int nkb = (j >> 2) + 1;
        for (int kt0 = 0; kt0 < nkb; ++kt0) {
            const int kb = kt0 * 64;
            bf16x8 kf[4][2];
#pragma unroll
            for (int kt = 0; kt < 4; kt++)
#pragma unroll
                for (int dk = 0; dk < 2; dk++)
                    kf[kt][dk] = *(const bf16x8*)(Kp + (size_t)(kb + kt * 16 + lr) * D + dk * 32 + lg * 8);
            f32x4 s[4] = {};
#pragma unroll
            for (int kt = 0; kt < 4; kt++)
#pragma unroll
                for (int dk = 0; dk < 2; dk++)
                    s[kt] = MFMA16(qa[dk], kf[kt][dk], s[kt]);

            // mask + scale + row-max (16-lane groups)
            float pmax[4];
#pragma unroll
            for (int r = 0; r < 4; r++) {
                const int qq = qrow0 + lg * 4 + r;
                float mt = -1e30f;
#pragma unroll
                for (int kt = 0; kt < 4; kt++) {
                    float v = (kb + kt * 16 + lr <= qq) ? s[kt][r] * 0.125f : -1e30f;
                    s[kt][r] = v;
                    mt = fmaxf(mt, v);
                }
#pragma unroll
                for (int off = 1; off < 16; off <<= 1)
                    mt = fmaxf(mt, __shfl_xor(mt, off));
                pmax[r] = mt;
            }

            // defer-max (T13): rescale only if some row's max grew by > 8
            int ok = 1;
#pragma unroll
            for (int r = 0; r < 4; r++)
                ok &= (pmax[r] <= mrow[r] + 8.0f) ? 1 : 0;
            if (!__all(ok)) {
#pragma unroll
                for (int r = 0; r < 4; r++) {
                    float mnew = fmaxf(mrow[r], pmax[r]);
                    float al = __expf(mrow[r] - mnew);
                    mrow[r] = mnew;
                    lrow[r] *= al;
#pragma unroll
                    for (int dt = 0; dt < 4; dt++) o[dt][r] *= al;
                }
            }

            // exp + row-sum
#pragma unroll
            for (int r = 0; r < 4; r++) {
                float rs = 0.f;
#pragma unroll
                for (int kt = 0; kt < 4; kt++) {
                    float p = __expf(s[kt][r] - mrow[r]);
                    s[kt][r] = p;
                    rs += p;
                }
#pragma unroll
                for (int off = 1; off < 16; off <<= 1)
                    rs += __shfl_xor(rs, off);
                lrow[r] += rs;
            }

            // P -> padded LDS slab (conflict-free) -> A-fragments
#pragma unroll
            for (int kt = 0; kt < 4; kt++)
#pragma unroll
                for (int r = 0; r < 4; r++)
                    plds[w][lg * 4 + r][kt * 16 + lr] = (__bf16)s[kt][r];

            bf16x8 pa[2];
#pragma unroll
            for (int kh = 0; kh < 2; kh++)
                pa[kh] = *(const bf16x8*)&plds[w][lr][kh * 32 + lg * 8];

#pragma unroll
            for (int kh = 0; kh < 2; kh++) {
                bf16x8 vf[4];
#pragma unroll
                for (int dt = 0; dt < 4; dt++)
                    vf[dt] = *(const bf16x8*)(Vp + (size_t)(dt * 16 + lr) * T + kb + kh * 32 + lg * 8);
#pragma unroll
                for (int dt = 0; dt < 4; dt++)
                    o[dt] = MFMA16(pa[kh], vf[dt], o[dt]);
            }
        }

#pragma unroll
        for (int dt = 0; dt < 4; dt++)
#pragma unroll
            for (int r = 0; r < 4; r++) {
                int qq = qrow0 + lg * 4 + r;
                int dd = dt * 16 + lr;
                float val = o[dt][r] / lrow[r];
                ATT[(size_t)(b_ * 2048 + qq) * 1024 + h * 64 + dd] = (__bf16)val;
            }
    }
}

// ---------------- proj GEMM (m97 structure): [8192,1024] @ [1024,1024]^T + bias ----
__global__ __launch_bounds__(256, 2) void proj_gemm(const __bf16* __restrict__ A,
                                                    const __bf16* __restrict__ W,
                                                    const float* __restrict__ bias,
                                                    float* __restrict__ out) {
    const int KD = 1024;
    __shared__ __align__(16) __bf16 As[128 * 32];
    __shared__ __align__(16) __bf16 Bs[128 * 32];
    const int tid = threadIdx.x;
    const int lane = tid & 63, w = tid >> 6;
    const int lr = lane & 15, lg = lane >> 4;
    const int row0 = blockIdx.y * 128, col0 = blockIdx.x * 128;
    const int wrow = (w >> 1) * 64, wcol = (w & 1) * 64;
    f32x4 acc[4][4] = {};
    const int c0 = tid, c1 = tid + 256;
    const __bf16* ga0 = A + (size_t)(row0 + (c0 >> 2)) * KD + (c0 & 3) * 8;
    const __bf16* ga1 = A + (size_t)(row0 + (c1 >> 2)) * KD + (c1 & 3) * 8;
    const __bf16* gb0 = W + (size_t)(col0 + (c0 >> 2)) * KD + (c0 & 3) * 8;
    const __bf16* gb1 = W + (size_t)(col0 + (c1 >> 2)) * KD + (c1 & 3) * 8;
    for (int k0 = 0; k0 < KD; k0 += 32) {
        __syncthreads();
        GLD16(ga0 + k0, As + c0 * 8);
        GLD16(ga1 + k0, As + c1 * 8);
        GLD16(gb0 + k0, Bs + c0 * 8);
        GLD16(gb1 + k0, Bs + c1 * 8);
        __syncthreads();
        bf16x8 a[4], b[4];
#pragma unroll
        for (int mi = 0; mi < 4; mi++)
            a[mi] = *(const bf16x8*)&As[(wrow + mi * 16 + lr) * 32 + lg * 8];
#pragma unroll
        for (int ni = 0; ni < 4; ni++)
            b[ni] = *(const bf16x8*)&Bs[(wcol + ni * 16 + lr) * 32 + lg * 8];
#pragma unroll
        for (int mi = 0; mi < 4; mi++)
#pragma unroll
            for (int ni = 0; ni < 4; ni++)
                acc[mi][ni] = MFMA16(a[mi], b[ni], acc[mi][ni]);
    }
#pragma unroll
    for (int mi = 0; mi < 4; mi++)
#pragma unroll
        for (int ni = 0; ni < 4; ni++)
#pragma unroll
            for (int r = 0; r < 4; r++) {
                int m = row0 + wrow + mi * 16 + lg * 4 + r;
                int n = col0 + wcol + ni * 16 + lr;
                out[(size_t)m * 1024 + n] = acc[mi][ni][r] + bias[n];
            }
}

extern "C" void kernel_launch(void* const* d_in, const int* in_sizes, int n_in,
                              void* d_out, int out_size, void* d_ws, size_t ws_size,
                              hipStream_t stream) {
    const float* x      = (const float*)d_in[0];
    const float* qkv_w  = (const float*)d_in[1];
    const float* qkv_b  = (const float*)d_in[2];
    const float* proj_w = (const float*)d_in[3];
    const float* proj_b = (const float*)d_in[4];
    float* out = (float*)d_out;
    char* ws = (char*)d_ws;

    // workspace layout (72 MB total)
    __bf16* xb    = (__bf16*)(ws);                         // 16 MB (reused as attb)
    __bf16* wqkv  = (__bf16*)(ws + 16777216);              //  6 MB
    __bf16* wproj = (__bf16*)(ws + 23068672);              //  2 MB
    __bf16* qb    = (__bf16*)(ws + 25165824);              // 16 MB
    __bf16* kb    = (__bf16*)(ws + 41943040);              // 16 MB
    __bf16* vtb   = (__bf16*)(ws + 58720256);              // 16 MB
    __bf16* attb  = xb;                                    // alias: x dead after QKV

    cvt_f32_bf16<<<2048, 256, 0, stream>>>(x,      xb,    4 * 2048 * 1024);
    cvt_f32_bf16<<<768,  256, 0, stream>>>(qkv_w,  wqkv,  3072 * 1024);
    cvt_f32_bf16<<<256,  256, 0, stream>>>(proj_w, wproj, 1024 * 1024);
    qkv_gemm<<<dim3(24, 64), 256, 0, stream>>>(xb, wqkv, qkv_b, qb, kb, vtb);
    attn_kernel<<<dim3(16, 64), 256, 0, stream>>>(qb, kb, vtb, attb);
    proj_gemm<<<dim3(8, 64), 256, 0, stream>>>(attb, wproj, proj_b, out);
}

// Round 4
// 314.188 us; speedup vs baseline: 1.2491x; 1.2491x over previous
//
#include <hip/hip_runtime.h>
#include <hip/hip_bf16.h>

typedef __bf16 bf16x8 __attribute__((ext_vector_type(8)));
typedef __bf16 bf16x4 __attribute__((ext_vector_type(4)));
typedef float  f32x4  __attribute__((ext_vector_type(4)));

#define MFMA16(a, b, c) __builtin_amdgcn_mfma_f32_16x16x32_bf16((a), (b), (c), 0, 0, 0)
#define GLD16(g, l)                                                              \
    __builtin_amdgcn_global_load_lds(                                            \
        (const __attribute__((address_space(1))) void*)(g),                      \
        (__attribute__((address_space(3))) void*)(l), 16, 0, 0)

// ---------------- fp32 -> bf16 convert (vectorized, grid-stride) ----------------
__global__ __launch_bounds__(256) void cvt_f32_bf16(const float* __restrict__ in,
                                                    __bf16* __restrict__ out, int n) {
    int stride = gridDim.x * blockDim.x * 4;
    for (int i = (blockIdx.x * blockDim.x + threadIdx.x) * 4; i < n; i += stride) {
        float4 v = *(const float4*)(in + i);
        bf16x4 o;
        o[0] = (__bf16)v.x; o[1] = (__bf16)v.y; o[2] = (__bf16)v.z; o[3] = (__bf16)v.w;
        *(bf16x4*)(out + i) = o;
    }
}

// ---------------- QKV GEMM (m97 structure): [8192,1024] @ [3072,1024]^T + bias ----
__global__ __launch_bounds__(256, 2) void qkv_gemm(const __bf16* __restrict__ X,
                                                   const __bf16* __restrict__ W,
                                                   const float* __restrict__ bias,
                                                   __bf16* __restrict__ Qo,
                                                   __bf16* __restrict__ Ko,
                                                   __bf16* __restrict__ VTo) {
    const int KD = 1024;
    __shared__ __align__(16) __bf16 As[128 * 32];
    __shared__ __align__(16) __bf16 Bs[128 * 32];
    const int tid = threadIdx.x;
    const int lane = tid & 63, w = tid >> 6;
    const int lr = lane & 15, lg = lane >> 4;
    const int row0 = blockIdx.y * 128, col0 = blockIdx.x * 128;
    const int wrow = (w >> 1) * 64, wcol = (w & 1) * 64;
    f32x4 acc[4][4] = {};
    const int c0 = tid, c1 = tid + 256;
    const __bf16* ga0 = X + (size_t)(row0 + (c0 >> 2)) * KD + (c0 & 3) * 8;
    const __bf16* ga1 = X + (size_t)(row0 + (c1 >> 2)) * KD + (c1 & 3) * 8;
    const __bf16* gb0 = W + (size_t)(col0 + (c0 >> 2)) * KD + (c0 & 3) * 8;
    const __bf16* gb1 = W + (size_t)(col0 + (c1 >> 2)) * KD + (c1 & 3) * 8;
    for (int k0 = 0; k0 < KD; k0 += 32) {
        __syncthreads();
        GLD16(ga0 + k0, As + c0 * 8);
        GLD16(ga1 + k0, As + c1 * 8);
        GLD16(gb0 + k0, Bs + c0 * 8);
        GLD16(gb1 + k0, Bs + c1 * 8);
        __syncthreads();
        bf16x8 a[4], b[4];
#pragma unroll
        for (int mi = 0; mi < 4; mi++)
            a[mi] = *(const bf16x8*)&As[(wrow + mi * 16 + lr) * 32 + lg * 8];
#pragma unroll
        for (int ni = 0; ni < 4; ni++)
            b[ni] = *(const bf16x8*)&Bs[(wcol + ni * 16 + lr) * 32 + lg * 8];
#pragma unroll
        for (int mi = 0; mi < 4; mi++)
#pragma unroll
            for (int ni = 0; ni < 4; ni++)
                acc[mi][ni] = MFMA16(a[mi], b[ni], acc[mi][ni]);
    }
#pragma unroll
    for (int mi = 0; mi < 4; mi++)
#pragma unroll
        for (int ni = 0; ni < 4; ni++)
#pragma unroll
            for (int r = 0; r < 4; r++) {
                int m = row0 + wrow + mi * 16 + lg * 4 + r;  // token row
                int n = col0 + wcol + ni * 16 + lr;          // channel (0..3071)
                float v = acc[mi][ni][r] + bias[n];
                int b_ = m >> 11, t = m & 2047;
                int sec = n >> 10, c = n & 1023;
                int h = c >> 6, d = c & 63;
                int bh = b_ * 16 + h;
                __bf16 bv = (__bf16)v;
                if (sec == 0)      Qo[(size_t)(bh * 2048 + t) * 64 + d] = bv;
                else if (sec == 1) Ko[(size_t)(bh * 2048 + t) * 64 + d] = bv;
                else               VTo[(size_t)(bh * 64 + d) * 2048 + t] = bv;
            }
}

// ---------------- causal flash attention (FA2 blocking, LDS-staged K/V) ----------
// Block = 128 q-rows (4 waves x QBLK=32). K [64][64] and V^T [64][64] tiles staged
// once per block via global_load_lds (linear dest + inverse-swizzled source), read
// with the matching XOR swizzle (sub ^= row&7 on 16B units) -> 2-way aliasing only.
// 1024 blocks, longest panel first, bijective XCD swizzle (bh-locality per XCD).
__global__ __launch_bounds__(256) void attn_kernel(const __bf16* __restrict__ Q,
                                                   const __bf16* __restrict__ Km,
                                                   const __bf16* __restrict__ VT,
                                                   __bf16* __restrict__ ATT) {
    const int T = 2048, D = 64;
    __shared__ __align__(16) __bf16 Ks[64 * 64];
    __shared__ __align__(16) __bf16 Vs[64 * 64];
    __shared__ __align__(16) __bf16 plds[4][32][68];
    const int tid = threadIdx.x;
    const int lane = tid & 63, w = tid >> 6;
    const int lr = lane & 15, lg = lane >> 4;
    // XCD-aware swizzle (1024 % 8 == 0 -> bijective): each XCD owns 8 bh.
    const int orig = blockIdx.x;
    const int wgid = (orig & 7) * 128 + (orig >> 3);
    const int bh = wgid >> 4;
    const int j = 15 - (wgid & 15);          // longest panel dispatched first
    const int qrow0 = j * 128 + w * 32;
    const int b_ = bh >> 4, h = bh & 15;
    const __bf16* Qp = Q + (size_t)bh * T * D;
    const __bf16* Kp = Km + (size_t)bh * T * D;
    const __bf16* Vp = VT + (size_t)bh * D * T;

    // Q fragments (registers, once)
    bf16x8 qa[2][2];
#pragma unroll
    for (int qt = 0; qt < 2; qt++)
#pragma unroll
        for (int dk = 0; dk < 2; dk++)
            qa[qt][dk] = *(const bf16x8*)(Qp + (size_t)(qrow0 + qt * 16 + lr) * D + dk * 32 + lg * 8);

    // staging sources: chunk c (0..511): row=c>>3, 16B-unit sub=c&7,
    // global column unit = sub ^ (row&7)  (involution; LDS dest stays linear)
    const int c0 = tid, c1 = tid + 256;
    const int r0 = c0 >> 3, s0 = (c0 & 7) ^ (r0 & 7);
    const int r1 = c1 >> 3, s1 = (c1 & 7) ^ (r1 & 7);
    const __bf16* kg0 = Kp + r0 * 64 + s0 * 8;
    const __bf16* kg1 = Kp + r1 * 64 + s1 * 8;
    const __bf16* vg0 = Vp + r0 * 2048 + s0 * 8;
    const __bf16* vg1 = Vp + r1 * 2048 + s1 * 8;

    float mrow[2][4], lrow[2][4];
#pragma unroll
    for (int qt = 0; qt < 2; qt++)
#pragma unroll
        for (int r = 0; r < 4; r++) { mrow[qt][r] = -1e30f; lrow[qt][r] = 0.f; }
    f32x4 o[2][4] = {};

    const int nkb = 2 * j + 2;               // k-blocks of 64 for this 128-row panel
    const int my_last = qrow0 + 31;          // wave's causal horizon
    for (int kt0 = 0; kt0 < nkb; ++kt0) {
        const int kb = kt0 * 64;
        __syncthreads();
        GLD16(kg0 + (size_t)kb * 64, Ks + c0 * 8);
        GLD16(kg1 + (size_t)kb * 64, Ks + c1 * 8);
        GLD16(vg0 + kb, Vs + c0 * 8);
        GLD16(vg1 + kb, Vs + c1 * 8);
        __syncthreads();
        if (kb <= my_last) {
            // K fragments from swizzled LDS
            bf16x8 kf[4][2];
#pragma unroll
            for (int kt = 0; kt < 4; kt++)
#pragma unroll
                for (int dk = 0; dk < 2; dk++)
                    kf[kt][dk] = *(const bf16x8*)&Ks[(kt * 16 + lr) * 64 + (((dk << 2) + lg) ^ (lr & 7)) * 8];
            f32x4 s[2][4] = {};
#pragma unroll
            for (int qt = 0; qt < 2; qt++)
#pragma unroll
                for (int kt = 0; kt < 4; kt++)
#pragma unroll
                    for (int dk = 0; dk < 2; dk++)
                        s[qt][kt] = MFMA16(qa[qt][dk], kf[kt][dk], s[qt][kt]);

            // mask + scale + row-max (16-lane groups)
            float pmax[2][4];
#pragma unroll
            for (int qt = 0; qt < 2; qt++)
#pragma unroll
                for (int r = 0; r < 4; r++) {
                    const int qq = qrow0 + qt * 16 + lg * 4 + r;
                    float mt = -1e30f;
#pragma unroll
                    for (int kt = 0; kt < 4; kt++) {
                        float v = (kb + kt * 16 + lr <= qq) ? s[qt][kt][r] * 0.125f : -1e30f;
                        s[qt][kt][r] = v;
                        mt = fmaxf(mt, v);
                    }
#pragma unroll
                    for (int off = 1; off < 16; off <<= 1)
                        mt = fmaxf(mt, __shfl_xor(mt, off));
                    pmax[qt][r] = mt;
                }

            // defer-max (T13)
            int ok = 1;
#pragma unroll
            for (int qt = 0; qt < 2; qt++)
#pragma unroll
                for (int r = 0; r < 4; r++)
                    ok &= (pmax[qt][r] <= mrow[qt][r] + 8.0f) ? 1 : 0;
            if (!__all(ok)) {
#pragma unroll
                for (int qt = 0; qt < 2; qt++)
#pragma unroll
                    for (int r = 0; r < 4; r++) {
                        float mnew = fmaxf(mrow[qt][r], pmax[qt][r]);
                        float al = __expf(mrow[qt][r] - mnew);
                        mrow[qt][r] = mnew;
                        lrow[qt][r] *= al;
#pragma unroll
                        for (int dt = 0; dt < 4; dt++) o[qt][dt][r] *= al;
                    }
            }

            // exp + row-sum
#pragma unroll
            for (int qt = 0; qt < 2; qt++)
#pragma unroll
                for (int r = 0; r < 4; r++) {
                    float rs = 0.f;
#pragma unroll
                    for (int kt = 0; kt < 4; kt++) {
                        float p = __expf(s[qt][kt][r] - mrow[qt][r]);
                        s[qt][kt][r] = p;
                        rs += p;
                    }
#pragma unroll
                    for (int off = 1; off < 16; off <<= 1)
                        rs += __shfl_xor(rs, off);
                    lrow[qt][r] += rs;
                }

            // P -> padded LDS slab (conflict-free) -> A-fragments
#pragma unroll
            for (int qt = 0; qt < 2; qt++)
#pragma unroll
                for (int kt = 0; kt < 4; kt++)
#pragma unroll
                    for (int r = 0; r < 4; r++)
                        plds[w][qt * 16 + lg * 4 + r][kt * 16 + lr] = (__bf16)s[qt][kt][r];

            bf16x8 pa[2][2];
#pragma unroll
            for (int qt = 0; qt < 2; qt++)
#pragma unroll
                for (int kh = 0; kh < 2; kh++)
                    pa[qt][kh] = *(const bf16x8*)&plds[w][qt * 16 + lr][kh * 32 + lg * 8];

#pragma unroll
            for (int kh = 0; kh < 2; kh++) {
                bf16x8 vf[4];
#pragma unroll
                for (int dt = 0; dt < 4; dt++)
                    vf[dt] = *(const bf16x8*)&Vs[(dt * 16 + lr) * 64 + (((kh << 2) + lg) ^ (lr & 7)) * 8];
#pragma unroll
                for (int qt = 0; qt < 2; qt++)
#pragma unroll
                    for (int dt = 0; dt < 4; dt++)
                        o[qt][dt] = MFMA16(pa[qt][kh], vf[dt], o[qt][dt]);
            }
        }
    }

#pragma unroll
    for (int qt = 0; qt < 2; qt++)
#pragma unroll
        for (int dt = 0; dt < 4; dt++)
#pragma unroll
            for (int r = 0; r < 4; r++) {
                int qq = qrow0 + qt * 16 + lg * 4 + r;
                int dd = dt * 16 + lr;
                float val = o[qt][dt][r] / lrow[qt][r];
                ATT[(size_t)(b_ * 2048 + qq) * 1024 + h * 64 + dd] = (__bf16)val;
            }
}

// ---------------- proj GEMM (m97 structure): [8192,1024] @ [1024,1024]^T + bias ----
__global__ __launch_bounds__(256, 2) void proj_gemm(const __bf16* __restrict__ A,
                                                    const __bf16* __restrict__ W,
                                                    const float* __restrict__ bias,
                                                    float* __restrict__ out) {
    const int KD = 1024;
    __shared__ __align__(16) __bf16 As[128 * 32];
    __shared__ __align__(16) __bf16 Bs[128 * 32];
    const int tid = threadIdx.x;
    const int lane = tid & 63, w = tid >> 6;
    const int lr = lane & 15, lg = lane >> 4;
    const int row0 = blockIdx.y * 128, col0 = blockIdx.x * 128;
    const int wrow = (w >> 1) * 64, wcol = (w & 1) * 64;
    f32x4 acc[4][4] = {};
    const int c0 = tid, c1 = tid + 256;
    const __bf16* ga0 = A + (size_t)(row0 + (c0 >> 2)) * KD + (c0 & 3) * 8;
    const __bf16* ga1 = A + (size_t)(row0 + (c1 >> 2)) * KD + (c1 & 3) * 8;
    const __bf16* gb0 = W + (size_t)(col0 + (c0 >> 2)) * KD + (c0 & 3) * 8;
    const __bf16* gb1 = W + (size_t)(col0 + (c1 >> 2)) * KD + (c1 & 3) * 8;
    for (int k0 = 0; k0 < KD; k0 += 32) {
        __syncthreads();
        GLD16(ga0 + k0, As + c0 * 8);
        GLD16(ga1 + k0, As + c1 * 8);
        GLD16(gb0 + k0, Bs + c0 * 8);
        GLD16(gb1 + k0, Bs + c1 * 8);
        __syncthreads();
        bf16x8 a[4], b[4];
#pragma unroll
        for (int mi = 0; mi < 4; mi++)
            a[mi] = *(const bf16x8*)&As[(wrow + mi * 16 + lr) * 32 + lg * 8];
#pragma unroll
        for (int ni = 0; ni < 4; ni++)
            b[ni] = *(const bf16x8*)&Bs[(wcol + ni * 16 + lr) * 32 + lg * 8];
#pragma unroll
        for (int mi = 0; mi < 4; mi++)
#pragma unroll
            for (int ni = 0; ni < 4; ni++)
                acc[mi][ni] = MFMA16(a[mi], b[ni], acc[mi][ni]);
    }
#pragma unroll
    for (int mi = 0; mi < 4; mi++)
#pragma unroll
        for (int ni = 0; ni < 4; ni++)
#pragma unroll
            for (int r = 0; r < 4; r++) {
                int m = row0 + wrow + mi * 16 + lg * 4 + r;
                int n = col0 + wcol + ni * 16 + lr;
                out[(size_t)m * 1024 + n] = acc[mi][ni][r] + bias[n];
            }
}

extern "C" void kernel_launch(void* const* d_in, const int* in_sizes, int n_in,
                              void* d_out, int out_size, void* d_ws, size_t ws_size,
                              hipStream_t stream) {
    const float* x      = (const float*)d_in[0];
    const float* qkv_w  = (const float*)d_in[1];
    const float* qkv_b  = (const float*)d_in[2];
    const float* proj_w = (const float*)d_in[3];
    const float* proj_b = (const float*)d_in[4];
    float* out = (float*)d_out;
    char* ws = (char*)d_ws;

    // workspace layout (72 MB total)
    __bf16* xb    = (__bf16*)(ws);                         // 16 MB (reused as attb)
    __bf16* wqkv  = (__bf16*)(ws + 16777216);              //  6 MB
    __bf16* wproj = (__bf16*)(ws + 23068672);              //  2 MB
    __bf16* qb    = (__bf16*)(ws + 25165824);              // 16 MB
    __bf16* kb    = (__bf16*)(ws + 41943040);              // 16 MB
    __bf16* vtb   = (__bf16*)(ws + 58720256);              // 16 MB
    __bf16* attb  = xb;                                    // alias: x dead after QKV

    cvt_f32_bf16<<<2048, 256, 0, stream>>>(x,      xb,    4 * 2048 * 1024);
    cvt_f32_bf16<<<768,  256, 0, stream>>>(qkv_w,  wqkv,  3072 * 1024);
    cvt_f32_bf16<<<256,  256, 0, stream>>>(proj_w, wproj, 1024 * 1024);
    qkv_gemm<<<dim3(24, 64), 256, 0, stream>>>(xb, wqkv, qkv_b, qb, kb, vtb);
    attn_kernel<<<1024, 256, 0, stream>>>(qb, kb, vtb, attb);
    proj_gemm<<<dim3(8, 64), 256, 0, stream>>>(attb, wproj, proj_b, out);
}

// Round 5
// 313.948 us; speedup vs baseline: 1.2500x; 1.0008x over previous
//
#include <hip/hip_runtime.h>
#include <hip/hip_bf16.h>

typedef __bf16 bf16x8 __attribute__((ext_vector_type(8)));
typedef __bf16 bf16x4 __attribute__((ext_vector_type(4)));
typedef float  f32x4  __attribute__((ext_vector_type(4)));

#define MFMA16(a, b, c) __builtin_amdgcn_mfma_f32_16x16x32_bf16((a), (b), (c), 0, 0, 0)
#define GLD16(g, l)                                                              \
    __builtin_amdgcn_global_load_lds(                                            \
        (const __attribute__((address_space(1))) void*)(g),                      \
        (__attribute__((address_space(3))) void*)(l), 16, 0, 0)

// ---------------- fp32 -> bf16 convert (vectorized, grid-stride) ----------------
__global__ __launch_bounds__(256) void cvt_f32_bf16(const float* __restrict__ in,
                                                    __bf16* __restrict__ out, int n) {
    int stride = gridDim.x * blockDim.x * 4;
    for (int i = (blockIdx.x * blockDim.x + threadIdx.x) * 4; i < n; i += stride) {
        float4 v = *(const float4*)(in + i);
        bf16x4 o;
        o[0] = (__bf16)v.x; o[1] = (__bf16)v.y; o[2] = (__bf16)v.z; o[3] = (__bf16)v.w;
        *(bf16x4*)(out + i) = o;
    }
}

// ---------------- QKV GEMM (m97 structure): [8192,1024] @ [3072,1024]^T + bias ----
__global__ __launch_bounds__(256, 2) void qkv_gemm(const __bf16* __restrict__ X,
                                                   const __bf16* __restrict__ W,
                                                   const float* __restrict__ bias,
                                                   __bf16* __restrict__ Qo,
                                                   __bf16* __restrict__ Ko,
                                                   __bf16* __restrict__ VTo) {
    const int KD = 1024;
    __shared__ __align__(16) __bf16 As[128 * 32];
    __shared__ __align__(16) __bf16 Bs[128 * 32];
    const int tid = threadIdx.x;
    const int lane = tid & 63, w = tid >> 6;
    const int lr = lane & 15, lg = lane >> 4;
    const int row0 = blockIdx.y * 128, col0 = blockIdx.x * 128;
    const int wrow = (w >> 1) * 64, wcol = (w & 1) * 64;
    f32x4 acc[4][4] = {};
    const int c0 = tid, c1 = tid + 256;
    const __bf16* ga0 = X + (size_t)(row0 + (c0 >> 2)) * KD + (c0 & 3) * 8;
    const __bf16* ga1 = X + (size_t)(row0 + (c1 >> 2)) * KD + (c1 & 3) * 8;
    const __bf16* gb0 = W + (size_t)(col0 + (c0 >> 2)) * KD + (c0 & 3) * 8;
    const __bf16* gb1 = W + (size_t)(col0 + (c1 >> 2)) * KD + (c1 & 3) * 8;
    for (int k0 = 0; k0 < KD; k0 += 32) {
        __syncthreads();
        GLD16(ga0 + k0, As + c0 * 8);
        GLD16(ga1 + k0, As + c1 * 8);
        GLD16(gb0 + k0, Bs + c0 * 8);
        GLD16(gb1 + k0, Bs + c1 * 8);
        __syncthreads();
        bf16x8 a[4], b[4];
#pragma unroll
        for (int mi = 0; mi < 4; mi++)
            a[mi] = *(const bf16x8*)&As[(wrow + mi * 16 + lr) * 32 + lg * 8];
#pragma unroll
        for (int ni = 0; ni < 4; ni++)
            b[ni] = *(const bf16x8*)&Bs[(wcol + ni * 16 + lr) * 32 + lg * 8];
#pragma unroll
        for (int mi = 0; mi < 4; mi++)
#pragma unroll
            for (int ni = 0; ni < 4; ni++)
                acc[mi][ni] = MFMA16(a[mi], b[ni], acc[mi][ni]);
    }
#pragma unroll
    for (int mi = 0; mi < 4; mi++)
#pragma unroll
        for (int ni = 0; ni < 4; ni++)
#pragma unroll
            for (int r = 0; r < 4; r++) {
                int m = row0 + wrow + mi * 16 + lg * 4 + r;  // token row
                int n = col0 + wcol + ni * 16 + lr;          // channel (0..3071)
                float v = acc[mi][ni][r] + bias[n];
                int b_ = m >> 11, t = m & 2047;
                int sec = n >> 10, c = n & 1023;
                int h = c >> 6, d = c & 63;
                int bh = b_ * 16 + h;
                __bf16 bv = (__bf16)v;
                if (sec == 0)      Qo[(size_t)(bh * 2048 + t) * 64 + d] = bv;
                else if (sec == 1) Ko[(size_t)(bh * 2048 + t) * 64 + d] = bv;
                else               VTo[(size_t)(bh * 64 + d) * 2048 + t] = bv;
            }
}

// ---------------- causal flash attention ------------------------------------
// 512 uniform blocks: block = pair of 128-row panels {15-idx, idx} processed
// sequentially (34 k-tiles total each) -> stable 2 blocks/CU the whole kernel.
// K/V tiles double-buffered in LDS, staged one tile ahead via global_load_lds
// (linear dest + inverse-swizzled source; reads use matching XOR swizzle).
// Wave-uniform unmasked fast path for tiles fully below the diagonal.
__global__ __launch_bounds__(256) void attn_kernel(const __bf16* __restrict__ Q,
                                                   const __bf16* __restrict__ Km,
                                                   const __bf16* __restrict__ VT,
                                                   __bf16* __restrict__ ATT) {
    const int T = 2048, D = 64;
    __shared__ __align__(16) __bf16 Ks[2][64 * 64];
    __shared__ __align__(16) __bf16 Vs[2][64 * 64];
    __shared__ __align__(16) __bf16 plds[4][32][68];
    const int tid = threadIdx.x;
    const int lane = tid & 63, w = tid >> 6;
    const int lr = lane & 15, lg = lane >> 4;
    // XCD-aware swizzle (512 % 8 == 0 -> bijective): each XCD owns 8 bh.
    const int orig = blockIdx.x;
    const int wgid = (orig & 7) * 64 + (orig >> 3);
    const int bh = wgid >> 3;
    const int pidx = wgid & 7;
    const int b_ = bh >> 4, h = bh & 15;
    const __bf16* Qp = Q + (size_t)bh * T * D;
    const __bf16* Kp = Km + (size_t)bh * T * D;
    const __bf16* Vp = VT + (size_t)bh * D * T;

    // staging sources: chunk c: row=c>>3, 16B-unit sub=c&7,
    // global column unit = sub ^ (row&7) (involution; LDS dest linear)
    const int c0 = tid, c1 = tid + 256;
    const int r0 = c0 >> 3, s0 = (c0 & 7) ^ (r0 & 7);
    const int r1 = c1 >> 3, s1 = (c1 & 7) ^ (r1 & 7);
    const __bf16* kg0 = Kp + r0 * 64 + s0 * 8;
    const __bf16* kg1 = Kp + r1 * 64 + s1 * 8;
    const __bf16* vg0 = Vp + r0 * 2048 + s0 * 8;
    const __bf16* vg1 = Vp + r1 * 2048 + s1 * 8;

    for (int pp = 0; pp < 2; ++pp) {
        const int j = pp ? pidx : 15 - pidx;   // long panel first
        const int qrow0 = j * 128 + w * 32;
        bf16x8 qa[2][2];
#pragma unroll
        for (int qt = 0; qt < 2; qt++)
#pragma unroll
            for (int dk = 0; dk < 2; dk++)
                qa[qt][dk] = *(const bf16x8*)(Qp + (size_t)(qrow0 + qt * 16 + lr) * D + dk * 32 + lg * 8);

        float mrow[2][4], lrow[2][4];
#pragma unroll
        for (int qt = 0; qt < 2; qt++)
#pragma unroll
            for (int r = 0; r < 4; r++) { mrow[qt][r] = -1e30f; lrow[qt][r] = 0.f; }
        f32x4 o[2][4] = {};

        const int nkb = 2 * j + 2;
        const int my_last = qrow0 + 31;

        // prologue: stage tile 0 into buffer 0
        GLD16(kg0, Ks[0] + c0 * 8);
        GLD16(kg1, Ks[0] + c1 * 8);
        GLD16(vg0, Vs[0] + c0 * 8);
        GLD16(vg1, Vs[0] + c1 * 8);
        __syncthreads();

        int cur = 0;
        for (int t = 0; t < nkb; ++t) {
            if (t + 1 < nkb) {   // stage next tile into the other buffer
                const size_t kof = (size_t)(t + 1) * 64 * 64;
                const size_t vof = (size_t)(t + 1) * 64;
                GLD16(kg0 + kof, Ks[cur ^ 1] + c0 * 8);
                GLD16(kg1 + kof, Ks[cur ^ 1] + c1 * 8);
                GLD16(vg0 + vof, Vs[cur ^ 1] + c0 * 8);
                GLD16(vg1 + vof, Vs[cur ^ 1] + c1 * 8);
            }
            const int kb = t * 64;
            if (kb <= my_last) {
                const __bf16* KsC = Ks[cur];
                const __bf16* VsC = Vs[cur];
                bf16x8 kf[4][2];
#pragma unroll
                for (int kt = 0; kt < 4; kt++)
#pragma unroll
                    for (int dk = 0; dk < 2; dk++)
                        kf[kt][dk] = *(const bf16x8*)&KsC[(kt * 16 + lr) * 64 + (((dk << 2) + lg) ^ (lr & 7)) * 8];
                f32x4 s[2][4] = {};
#pragma unroll
                for (int qt = 0; qt < 2; qt++)
#pragma unroll
                    for (int kt = 0; kt < 4; kt++)
#pragma unroll
                        for (int dk = 0; dk < 2; dk++)
                            s[qt][kt] = MFMA16(qa[qt][dk], kf[kt][dk], s[qt][kt]);

                // scale (+ mask only on diagonal tiles) + row-max
                float pmax[2][4];
                if (kb + 64 <= qrow0) {  // wave-uniform: fully unmasked tile
#pragma unroll
                    for (int qt = 0; qt < 2; qt++)
#pragma unroll
                        for (int r = 0; r < 4; r++) {
                            float mt = -1e30f;
#pragma unroll
                            for (int kt = 0; kt < 4; kt++) {
                                float v = s[qt][kt][r] * 0.125f;
                                s[qt][kt][r] = v;
                                mt = fmaxf(mt, v);
                            }
#pragma unroll
                            for (int off = 1; off < 16; off <<= 1)
                                mt = fmaxf(mt, __shfl_xor(mt, off));
                            pmax[qt][r] = mt;
                        }
                } else {
#pragma unroll
                    for (int qt = 0; qt < 2; qt++)
#pragma unroll
                        for (int r = 0; r < 4; r++) {
                            const int qq = qrow0 + qt * 16 + lg * 4 + r;
                            float mt = -1e30f;
#pragma unroll
                            for (int kt = 0; kt < 4; kt++) {
                                float v = (kb + kt * 16 + lr <= qq) ? s[qt][kt][r] * 0.125f : -1e30f;
                                s[qt][kt][r] = v;
                                mt = fmaxf(mt, v);
                            }
#pragma unroll
                            for (int off = 1; off < 16; off <<= 1)
                                mt = fmaxf(mt, __shfl_xor(mt, off));
                            pmax[qt][r] = mt;
                        }
                }

                // defer-max (T13)
                int ok = 1;
#pragma unroll
                for (int qt = 0; qt < 2; qt++)
#pragma unroll
                    for (int r = 0; r < 4; r++)
                        ok &= (pmax[qt][r] <= mrow[qt][r] + 8.0f) ? 1 : 0;
                if (!__all(ok)) {
#pragma unroll
                    for (int qt = 0; qt < 2; qt++)
#pragma unroll
                        for (int r = 0; r < 4; r++) {
                            float mnew = fmaxf(mrow[qt][r], pmax[qt][r]);
                            float al = __expf(mrow[qt][r] - mnew);
                            mrow[qt][r] = mnew;
                            lrow[qt][r] *= al;
#pragma unroll
                            for (int dt = 0; dt < 4; dt++) o[qt][dt][r] *= al;
                        }
                }

                // exp + row-sum
#pragma unroll
                for (int qt = 0; qt < 2; qt++)
#pragma unroll
                    for (int r = 0; r < 4; r++) {
                        float rs = 0.f;
#pragma unroll
                        for (int kt = 0; kt < 4; kt++) {
                            float p = __expf(s[qt][kt][r] - mrow[qt][r]);
                            s[qt][kt][r] = p;
                            rs += p;
                        }
#pragma unroll
                        for (int off = 1; off < 16; off <<= 1)
                            rs += __shfl_xor(rs, off);
                        lrow[qt][r] += rs;
                    }

                // P -> padded LDS slab (conflict-free) -> A-fragments
#pragma unroll
                for (int qt = 0; qt < 2; qt++)
#pragma unroll
                    for (int kt = 0; kt < 4; kt++)
#pragma unroll
                        for (int r = 0; r < 4; r++)
                            plds[w][qt * 16 + lg * 4 + r][kt * 16 + lr] = (__bf16)s[qt][kt][r];

                bf16x8 pa[2][2];
#pragma unroll
                for (int qt = 0; qt < 2; qt++)
#pragma unroll
                    for (int kh = 0; kh < 2; kh++)
                        pa[qt][kh] = *(const bf16x8*)&plds[w][qt * 16 + lr][kh * 32 + lg * 8];

#pragma unroll
                for (int kh = 0; kh < 2; kh++) {
                    bf16x8 vf[4];
#pragma unroll
                    for (int dt = 0; dt < 4; dt++)
                        vf[dt] = *(const bf16x8*)&VsC[(dt * 16 + lr) * 64 + (((kh << 2) + lg) ^ (lr & 7)) * 8];
#pragma unroll
                    for (int qt = 0; qt < 2; qt++)
#pragma unroll
                        for (int dt = 0; dt < 4; dt++)
                            o[qt][dt] = MFMA16(pa[qt][kh], vf[dt], o[qt][dt]);
                }
            }
            __syncthreads();
            cur ^= 1;
        }

#pragma unroll
        for (int qt = 0; qt < 2; qt++)
#pragma unroll
            for (int dt = 0; dt < 4; dt++)
#pragma unroll
                for (int r = 0; r < 4; r++) {
                    int qq = qrow0 + qt * 16 + lg * 4 + r;
                    int dd = dt * 16 + lr;
                    float val = o[qt][dt][r] / lrow[qt][r];
                    ATT[(size_t)(b_ * 2048 + qq) * 1024 + h * 64 + dd] = (__bf16)val;
                }
    }
}

// ---------------- proj GEMM (m97 structure): [8192,1024] @ [1024,1024]^T + bias ----
__global__ __launch_bounds__(256, 2) void proj_gemm(const __bf16* __restrict__ A,
                                                    const __bf16* __restrict__ W,
                                                    const float* __restrict__ bias,
                                                    float* __restrict__ out) {
    const int KD = 1024;
    __shared__ __align__(16) __bf16 As[128 * 32];
    __shared__ __align__(16) __bf16 Bs[128 * 32];
    const int tid = threadIdx.x;
    const int lane = tid & 63, w = tid >> 6;
    const int lr = lane & 15, lg = lane >> 4;
    const int row0 = blockIdx.y * 128, col0 = blockIdx.x * 128;
    const int wrow = (w >> 1) * 64, wcol = (w & 1) * 64;
    f32x4 acc[4][4] = {};
    const int c0 = tid, c1 = tid + 256;
    const __bf16* ga0 = A + (size_t)(row0 + (c0 >> 2)) * KD + (c0 & 3) * 8;
    const __bf16* ga1 = A + (size_t)(row0 + (c1 >> 2)) * KD + (c1 & 3) * 8;
    const __bf16* gb0 = W + (size_t)(col0 + (c0 >> 2)) * KD + (c0 & 3) * 8;
    const __bf16* gb1 = W + (size_t)(col0 + (c1 >> 2)) * KD + (c1 & 3) * 8;
    for (int k0 = 0; k0 < KD; k0 += 32) {
        __syncthreads();
        GLD16(ga0 + k0, As + c0 * 8);
        GLD16(ga1 + k0, As + c1 * 8);
        GLD16(gb0 + k0, Bs + c0 * 8);
        GLD16(gb1 + k0, Bs + c1 * 8);
        __syncthreads();
        bf16x8 a[4], b[4];
#pragma unroll
        for (int mi = 0; mi < 4; mi++)
            a[mi] = *(const bf16x8*)&As[(wrow + mi * 16 + lr) * 32 + lg * 8];
#pragma unroll
        for (int ni = 0; ni < 4; ni++)
            b[ni] = *(const bf16x8*)&Bs[(wcol + ni * 16 + lr) * 32 + lg * 8];
#pragma unroll
        for (int mi = 0; mi < 4; mi++)
#pragma unroll
            for (int ni = 0; ni < 4; ni++)
                acc[mi][ni] = MFMA16(a[mi], b[ni], acc[mi][ni]);
    }
#pragma unroll
    for (int mi = 0; mi < 4; mi++)
#pragma unroll
        for (int ni = 0; ni < 4; ni++)
#pragma unroll
            for (int r = 0; r < 4; r++) {
                int m = row0 + wrow + mi * 16 + lg * 4 + r;
                int n = col0 + wcol + ni * 16 + lr;
                out[(size_t)m * 1024 + n] = acc[mi][ni][r] + bias[n];
            }
}

extern "C" void kernel_launch(void* const* d_in, const int* in_sizes, int n_in,
                              void* d_out, int out_size, void* d_ws, size_t ws_size,
                              hipStream_t stream) {
    const float* x      = (const float*)d_in[0];
    const float* qkv_w  = (const float*)d_in[1];
    const float* qkv_b  = (const float*)d_in[2];
    const float* proj_w = (const float*)d_in[3];
    const float* proj_b = (const float*)d_in[4];
    float* out = (float*)d_out;
    char* ws = (char*)d_ws;

    // workspace layout (72 MB total)
    __bf16* xb    = (__bf16*)(ws);                         // 16 MB (reused as attb)
    __bf16* wqkv  = (__bf16*)(ws + 16777216);              //  6 MB
    __bf16* wproj = (__bf16*)(ws + 23068672);              //  2 MB
    __bf16* qb    = (__bf16*)(ws + 25165824);              // 16 MB
    __bf16* kb    = (__bf16*)(ws + 41943040);              // 16 MB
    __bf16* vtb   = (__bf16*)(ws + 58720256);              // 16 MB
    __bf16* attb  = xb;                                    // alias: x dead after QKV

    cvt_f32_bf16<<<2048, 256, 0, stream>>>(x,      xb,    4 * 2048 * 1024);
    cvt_f32_bf16<<<768,  256, 0, stream>>>(qkv_w,  wqkv,  3072 * 1024);
    cvt_f32_bf16<<<256,  256, 0, stream>>>(proj_w, wproj, 1024 * 1024);
    qkv_gemm<<<dim3(24, 64), 256, 0, stream>>>(xb, wqkv, qkv_b, qb, kb, vtb);
    attn_kernel<<<512, 256, 0, stream>>>(qb, kb, vtb, attb);
    proj_gemm<<<dim3(8, 64), 256, 0, stream>>>(attb, wproj, proj_b, out);
}

// Round 6
// 260.328 us; speedup vs baseline: 1.5075x; 1.2060x over previous
//
#include <hip/hip_runtime.h>
#include <hip/hip_bf16.h>

typedef __bf16 bf16x8 __attribute__((ext_vector_type(8)));
typedef __bf16 bf16x4 __attribute__((ext_vector_type(4)));
typedef float  f32x4  __attribute__((ext_vector_type(4)));

#define MFMA16(a, b, c) __builtin_amdgcn_mfma_f32_16x16x32_bf16((a), (b), (c), 0, 0, 0)
#define GLD16(g, l)                                                              \
    __builtin_amdgcn_global_load_lds(                                            \
        (const __attribute__((address_space(1))) void*)(g),                      \
        (__attribute__((address_space(3))) void*)(l), 16, 0, 0)

// ---------------- fp32 -> bf16 convert (vectorized, grid-stride) ----------------
__global__ __launch_bounds__(256) void cvt_f32_bf16(const float* __restrict__ in,
                                                    __bf16* __restrict__ out, int n) {
    int stride = gridDim.x * blockDim.x * 4;
    for (int i = (blockIdx.x * blockDim.x + threadIdx.x) * 4; i < n; i += stride) {
        float4 v = *(const float4*)(in + i);
        bf16x4 o;
        o[0] = (__bf16)v.x; o[1] = (__bf16)v.y; o[2] = (__bf16)v.z; o[3] = (__bf16)v.w;
        *(bf16x4*)(out + i) = o;
    }
}

// ---------------- QKV GEMM (m97 structure): [8192,1024] @ [3072,1024]^T + bias ----
__global__ __launch_bounds__(256, 2) void qkv_gemm(const __bf16* __restrict__ X,
                                                   const __bf16* __restrict__ W,
                                                   const float* __restrict__ bias,
                                                   __bf16* __restrict__ Qo,
                                                   __bf16* __restrict__ Ko,
                                                   __bf16* __restrict__ VTo) {
    const int KD = 1024;
    __shared__ __align__(16) __bf16 As[128 * 32];
    __shared__ __align__(16) __bf16 Bs[128 * 32];
    const int tid = threadIdx.x;
    const int lane = tid & 63, w = tid >> 6;
    const int lr = lane & 15, lg = lane >> 4;
    const int row0 = blockIdx.y * 128, col0 = blockIdx.x * 128;
    const int wrow = (w >> 1) * 64, wcol = (w & 1) * 64;
    f32x4 acc[4][4] = {};
    const int c0 = tid, c1 = tid + 256;
    const __bf16* ga0 = X + (size_t)(row0 + (c0 >> 2)) * KD + (c0 & 3) * 8;
    const __bf16* ga1 = X + (size_t)(row0 + (c1 >> 2)) * KD + (c1 & 3) * 8;
    const __bf16* gb0 = W + (size_t)(col0 + (c0 >> 2)) * KD + (c0 & 3) * 8;
    const __bf16* gb1 = W + (size_t)(col0 + (c1 >> 2)) * KD + (c1 & 3) * 8;
    for (int k0 = 0; k0 < KD; k0 += 32) {
        __syncthreads();
        GLD16(ga0 + k0, As + c0 * 8);
        GLD16(ga1 + k0, As + c1 * 8);
        GLD16(gb0 + k0, Bs + c0 * 8);
        GLD16(gb1 + k0, Bs + c1 * 8);
        __syncthreads();
        bf16x8 a[4], b[4];
#pragma unroll
        for (int mi = 0; mi < 4; mi++)
            a[mi] = *(const bf16x8*)&As[(wrow + mi * 16 + lr) * 32 + lg * 8];
#pragma unroll
        for (int ni = 0; ni < 4; ni++)
            b[ni] = *(const bf16x8*)&Bs[(wcol + ni * 16 + lr) * 32 + lg * 8];
#pragma unroll
        for (int mi = 0; mi < 4; mi++)
#pragma unroll
            for (int ni = 0; ni < 4; ni++)
                acc[mi][ni] = MFMA16(a[mi], b[ni], acc[mi][ni]);
    }
#pragma unroll
    for (int mi = 0; mi < 4; mi++)
#pragma unroll
        for (int ni = 0; ni < 4; ni++)
#pragma unroll
            for (int r = 0; r < 4; r++) {
                int m = row0 + wrow + mi * 16 + lg * 4 + r;  // token row
                int n = col0 + wcol + ni * 16 + lr;          // channel (0..3071)
                float v = acc[mi][ni][r] + bias[n];
                int b_ = m >> 11, t = m & 2047;
                int sec = n >> 10, c = n & 1023;
                int h = c >> 6, d = c & 63;
                int bh = b_ * 16 + h;
                __bf16 bv = (__bf16)v;
                if (sec == 0)      Qo[(size_t)(bh * 2048 + t) * 64 + d] = bv;
                else if (sec == 1) Ko[(size_t)(bh * 2048 + t) * 64 + d] = bv;
                else               VTo[(size_t)(bh * 64 + d) * 2048 + t] = bv;
            }
}

// ---------------- causal flash attention (round-2 structure, dedup'd) ------------
// 512 blocks (flat, XCD-swizzled: each XCD owns 8 contiguous bh). idx 0..31 per bh;
// wave processes q-tile pair {idx, 63-idx} -> exactly 33 k-tiles of 64 per wave,
// each q-tile computed exactly once. Direct global K/V fragment loads (L2-fed).
// Common path has NO cross-lane ops: per-lane defer-max check (T13) + per-lane
// partial row-sum, reduced once after the k-loop. Padded P slab (0 conflicts).
__global__ __launch_bounds__(256) void attn_kernel(const __bf16* __restrict__ Q,
                                                   const __bf16* __restrict__ Km,
                                                   const __bf16* __restrict__ VT,
                                                   __bf16* __restrict__ ATT) {
    const int T = 2048, D = 64;
    __shared__ __align__(16) __bf16 plds[4][32][68];  // padded: conflict-free
    const int lane = threadIdx.x & 63, w = threadIdx.x >> 6;
    const int lr = lane & 15, lg = lane >> 4;
    // bijective XCD swizzle (512 % 8 == 0): wgid = (orig%8)*64 + orig/8
    const int orig = blockIdx.x;
    const int wgid = (orig & 7) * 64 + (orig >> 3);
    const int bh = wgid >> 3;                 // 8 blocks per bh
    const int idx = (wgid & 7) * 4 + w;       // 0..31
    const int b_ = bh >> 4, h = bh & 15;
    const __bf16* Qp = Q + (size_t)bh * T * D;
    const __bf16* Kp = Km + (size_t)bh * T * D;
    const __bf16* Vp = VT + (size_t)bh * D * T;

    for (int ph = 0; ph < 2; ++ph) {
        const int j = ph ? 63 - idx : idx;
        const int qrow0 = j * 32;
        bf16x8 qa[2][2];
#pragma unroll
        for (int qt = 0; qt < 2; qt++)
#pragma unroll
            for (int dk = 0; dk < 2; dk++)
                qa[qt][dk] = *(const bf16x8*)(Qp + (size_t)(qrow0 + qt * 16 + lr) * D + dk * 32 + lg * 8);

        float mrow[2][4], lsum[2][4];
#pragma unroll
        for (int qt = 0; qt < 2; qt++)
#pragma unroll
            for (int r = 0; r < 4; r++) { mrow[qt][r] = -1e30f; lsum[qt][r] = 0.f; }
        f32x4 o[2][4] = {};

        const int nkb = (j + 2) >> 1;
        for (int kt0 = 0; kt0 < nkb; ++kt0) {
            const int kb = kt0 * 64;
            bf16x8 kf[4][2];
#pragma unroll
            for (int kt = 0; kt < 4; kt++)
#pragma unroll
                for (int dk = 0; dk < 2; dk++)
                    kf[kt][dk] = *(const bf16x8*)(Kp + (size_t)(kb + kt * 16 + lr) * D + dk * 32 + lg * 8);
            f32x4 s[2][4] = {};
#pragma unroll
            for (int qt = 0; qt < 2; qt++)
#pragma unroll
                for (int kt = 0; kt < 4; kt++)
#pragma unroll
                    for (int dk = 0; dk < 2; dk++)
                        s[qt][kt] = MFMA16(qa[qt][dk], kf[kt][dk], s[qt][kt]);

            // mask + scale + per-lane local max (no cross-lane ops)
            float lmax[2][4];
            int flag = 0;
#pragma unroll
            for (int qt = 0; qt < 2; qt++)
#pragma unroll
                for (int r = 0; r < 4; r++) {
                    const int qq = qrow0 + qt * 16 + lg * 4 + r;
                    float mt = -1e30f;
#pragma unroll
                    for (int kt = 0; kt < 4; kt++) {
                        float v = (kb + kt * 16 + lr <= qq) ? s[qt][kt][r] * 0.125f : -1e30f;
                        s[qt][kt][r] = v;
                        mt = fmaxf(mt, v);
                    }
                    lmax[qt][r] = mt;
                    flag |= (mt > mrow[qt][r] + 8.0f) ? 1 : 0;
                }

            // defer-max (T13): full reduce + rescale only when some row grew > 8
            if (__any(flag)) {
#pragma unroll
                for (int qt = 0; qt < 2; qt++)
#pragma unroll
                    for (int r = 0; r < 4; r++) {
                        float mt = lmax[qt][r];
#pragma unroll
                        for (int off = 1; off < 16; off <<= 1)
                            mt = fmaxf(mt, __shfl_xor(mt, off));
                        float mnew = fmaxf(mrow[qt][r], mt);
                        float al = __expf(mrow[qt][r] - mnew);
                        mrow[qt][r] = mnew;
                        lsum[qt][r] *= al;
#pragma unroll
                        for (int dt = 0; dt < 4; dt++) o[qt][dt][r] *= al;
                    }
            }

            // exp + per-lane partial row-sum (no cross-lane ops)
#pragma unroll
            for (int qt = 0; qt < 2; qt++)
#pragma unroll
                for (int r = 0; r < 4; r++) {
                    float rs = 0.f;
#pragma unroll
                    for (int kt = 0; kt < 4; kt++) {
                        float p = __expf(s[qt][kt][r] - mrow[qt][r]);
                        s[qt][kt][r] = p;
                        rs += p;
                    }
                    lsum[qt][r] += rs;
                }

            // P -> padded LDS slab (conflict-free) -> A-fragments
#pragma unroll
            for (int qt = 0; qt < 2; qt++)
#pragma unroll
                for (int kt = 0; kt < 4; kt++)
#pragma unroll
                    for (int r = 0; r < 4; r++)
                        plds[w][qt * 16 + lg * 4 + r][kt * 16 + lr] = (__bf16)s[qt][kt][r];

            bf16x8 pa[2][2];
#pragma unroll
            for (int qt = 0; qt < 2; qt++)
#pragma unroll
                for (int kh = 0; kh < 2; kh++)
                    pa[qt][kh] = *(const bf16x8*)&plds[w][qt * 16 + lr][kh * 32 + lg * 8];

#pragma unroll
            for (int kh = 0; kh < 2; kh++) {
                bf16x8 vf[4];
#pragma unroll
                for (int dt = 0; dt < 4; dt++)
                    vf[dt] = *(const bf16x8*)(Vp + (size_t)(dt * 16 + lr) * T + kb + kh * 32 + lg * 8);
#pragma unroll
                for (int qt = 0; qt < 2; qt++)
#pragma unroll
                    for (int dt = 0; dt < 4; dt++)
                        o[qt][dt] = MFMA16(pa[qt][kh], vf[dt], o[qt][dt]);
            }
        }

        // final row-sum reduce (once per panel) + normalize + store
#pragma unroll
        for (int qt = 0; qt < 2; qt++)
#pragma unroll
            for (int r = 0; r < 4; r++) {
                float rs = lsum[qt][r];
#pragma unroll
                for (int off = 1; off < 16; off <<= 1)
                    rs += __shfl_xor(rs, off);
                lsum[qt][r] = 1.0f / rs;
            }
#pragma unroll
        for (int qt = 0; qt < 2; qt++)
#pragma unroll
            for (int dt = 0; dt < 4; dt++)
#pragma unroll
                for (int r = 0; r < 4; r++) {
                    int qq = qrow0 + qt * 16 + lg * 4 + r;
                    int dd = dt * 16 + lr;
                    float val = o[qt][dt][r] * lsum[qt][r];
                    ATT[(size_t)(b_ * 2048 + qq) * 1024 + h * 64 + dd] = (__bf16)val;
                }
    }
}

// ---------------- proj GEMM (m97 structure): [8192,1024] @ [1024,1024]^T + bias ----
__global__ __launch_bounds__(256, 2) void proj_gemm(const __bf16* __restrict__ A,
                                                    const __bf16* __restrict__ W,
                                                    const float* __restrict__ bias,
                                                    float* __restrict__ out) {
    const int KD = 1024;
    __shared__ __align__(16) __bf16 As[128 * 32];
    __shared__ __align__(16) __bf16 Bs[128 * 32];
    const int tid = threadIdx.x;
    const int lane = tid & 63, w = tid >> 6;
    const int lr = lane & 15, lg = lane >> 4;
    const int row0 = blockIdx.y * 128, col0 = blockIdx.x * 128;
    const int wrow = (w >> 1) * 64, wcol = (w & 1) * 64;
    f32x4 acc[4][4] = {};
    const int c0 = tid, c1 = tid + 256;
    const __bf16* ga0 = A + (size_t)(row0 + (c0 >> 2)) * KD + (c0 & 3) * 8;
    const __bf16* ga1 = A + (size_t)(row0 + (c1 >> 2)) * KD + (c1 & 3) * 8;
    const __bf16* gb0 = W + (size_t)(col0 + (c0 >> 2)) * KD + (c0 & 3) * 8;
    const __bf16* gb1 = W + (size_t)(col0 + (c1 >> 2)) * KD + (c1 & 3) * 8;
    for (int k0 = 0; k0 < KD; k0 += 32) {
        __syncthreads();
        GLD16(ga0 + k0, As + c0 * 8);
        GLD16(ga1 + k0, As + c1 * 8);
        GLD16(gb0 + k0, Bs + c0 * 8);
        GLD16(gb1 + k0, Bs + c1 * 8);
        __syncthreads();
        bf16x8 a[4], b[4];
#pragma unroll
        for (int mi = 0; mi < 4; mi++)
            a[mi] = *(const bf16x8*)&As[(wrow + mi * 16 + lr) * 32 + lg * 8];
#pragma unroll
        for (int ni = 0; ni < 4; ni++)
            b[ni] = *(const bf16x8*)&Bs[(wcol + ni * 16 + lr) * 32 + lg * 8];
#pragma unroll
        for (int mi = 0; mi < 4; mi++)
#pragma unroll
            for (int ni = 0; ni < 4; ni++)
                acc[mi][ni] = MFMA16(a[mi], b[ni], acc[mi][ni]);
    }
#pragma unroll
    for (int mi = 0; mi < 4; mi++)
#pragma unroll
        for (int ni = 0; ni < 4; ni++)
#pragma unroll
            for (int r = 0; r < 4; r++) {
                int m = row0 + wrow + mi * 16 + lg * 4 + r;
                int n = col0 + wcol + ni * 16 + lr;
                out[(size_t)m * 1024 + n] = acc[mi][ni][r] + bias[n];
            }
}

extern "C" void kernel_launch(void* const* d_in, const int* in_sizes, int n_in,
                              void* d_out, int out_size, void* d_ws, size_t ws_size,
                              hipStream_t stream) {
    const float* x      = (const float*)d_in[0];
    const float* qkv_w  = (const float*)d_in[1];
    const float* qkv_b  = (const float*)d_in[2];
    const float* proj_w = (const float*)d_in[3];
    const float* proj_b = (const float*)d_in[4];
    float* out = (float*)d_out;
    char* ws = (char*)d_ws;

    // workspace layout (72 MB total)
    __bf16* xb    = (__bf16*)(ws);                         // 16 MB (reused as attb)
    __bf16* wqkv  = (__bf16*)(ws + 16777216);              //  6 MB
    __bf16* wproj = (__bf16*)(ws + 23068672);              //  2 MB
    __bf16* qb    = (__bf16*)(ws + 25165824);              // 16 MB
    __bf16* kb    = (__bf16*)(ws + 41943040);              // 16 MB
    __bf16* vtb   = (__bf16*)(ws + 58720256);              // 16 MB
    __bf16* attb  = xb;                                    // alias: x dead after QKV

    cvt_f32_bf16<<<2048, 256, 0, stream>>>(x,      xb,    4 * 2048 * 1024);
    cvt_f32_bf16<<<768,  256, 0, stream>>>(qkv_w,  wqkv,  3072 * 1024);
    cvt_f32_bf16<<<256,  256, 0, stream>>>(proj_w, wproj, 1024 * 1024);
    qkv_gemm<<<dim3(24, 64), 256, 0, stream>>>(xb, wqkv, qkv_b, qb, kb, vtb);
    attn_kernel<<<512, 256, 0, stream>>>(qb, kb, vtb, attb);
    proj_gemm<<<dim3(8, 64), 256, 0, stream>>>(attb, wproj, proj_b, out);
}